// Round 4
// baseline (71.045 us; speedup 1.0000x reference)
//
#include <hip/hip_runtime.h>

// Problem constants (fixed by setup_inputs): B=4, C=32, H=64, W=128, D=192/4=48.
#define B_  4
#define C_  32
#define H_  64
#define W_  128
#define D_  48

typedef float f32x4 __attribute__((ext_vector_type(4)));

// Output: (B, 2C, D, H, W) float32.
//   ch <  C : out = left[b][ch][h][w]                      (broadcast over d)
//   ch >= C : out = (w+d < W) ? right[b][ch-C][h][w+d] : 0
//
// Block = (z = b*2C+ch, group of 4 consecutive d). Each block writes 4 d-planes
// x 64 h-rows = 4 sequential 32KB streams over a 128KB contiguous span (vs 48
// interleaved 4KB-chunk streams before) -> better HBM write efficiency.
// No LDS: the shifted gather is 2 aligned 16B global loads (L2-hot) + register
// shuffles; boundary zeros via loop-invariant per-element selects.
// Grid = (12, 256) = 3072 blocks = 12 blocks/CU, no LDS/sync -> high occupancy.
__global__ __launch_bounds__(256) void CostVolume_66529043415444_kernel(
    const float* __restrict__ left,
    const float* __restrict__ right,
    float* __restrict__ out)
{
    const int tid = threadIdx.x;
    const int w4  = tid & 31;            // float4 index within row: 0..31
    const int hs  = tid >> 5;            // 0..7
    const int d0  = (int)blockIdx.x * 4; // 0,4,...,44
    const int z   = (int)blockIdx.y;     // b*64 + ch
    const int ch  = z & 63;
    const int b   = z >> 6;

    f32x4* __restrict__ out4 = reinterpret_cast<f32x4*>(out);
    const size_t pstr  = (size_t)H_ * (W_ / 4);       // 2048 float4 per d-plane
    const size_t zbase = (size_t)z * D_ * pstr;

    if (ch < C_) {
        // left broadcast: one aligned load per row, 4 plane-stores
        const f32x4* __restrict__ l4 = reinterpret_cast<const f32x4*>(left);
        const size_t lbase = ((size_t)b * C_ + ch) * H_;
        #pragma unroll
        for (int hi = 0; hi < 8; ++hi) {
            const int h = hi * 8 + hs;
            const f32x4 v = l4[(lbase + h) * (W_ / 4) + w4];
            #pragma unroll
            for (int r = 0; r < 4; ++r)
                __builtin_nontemporal_store(
                    v, &out4[zbase + (size_t)(d0 + r) * pstr + (size_t)h * (W_ / 4) + w4]);
        }
    } else {
        const int c = ch - C_;
        // window start (float index into the row): sources for (d0+r, w=4*w4+j)
        // are row[s + r + j], r+j in 0..6
        const int s  = 4 * w4 + d0;                   // 0..168, multiple of 4
        const int ka = (s     <= 124) ? s     : 124;  // clamped aligned loads
        const int kb = (s + 4 <= 124) ? s + 4 : 124;
        bool m[7];
        #pragma unroll
        for (int i = 0; i < 7; ++i) m[i] = (s + i) < W_;

        const float* __restrict__ img = right + ((size_t)b * C_ + c) * H_ * W_;
        #pragma unroll
        for (int hi = 0; hi < 8; ++hi) {
            const int h = hi * 8 + hs;
            const float* __restrict__ row = img + (size_t)h * W_;
            const f32x4 a  = *reinterpret_cast<const f32x4*>(row + ka);
            const f32x4 bb = *reinterpret_cast<const f32x4*>(row + kb);
            const float e[8] = {a.x, a.y, a.z, a.w, bb.x, bb.y, bb.z, bb.w};
            #pragma unroll
            for (int r = 0; r < 4; ++r) {
                const f32x4 v = { m[r]     ? e[r]     : 0.f,
                                  m[r + 1] ? e[r + 1] : 0.f,
                                  m[r + 2] ? e[r + 2] : 0.f,
                                  m[r + 3] ? e[r + 3] : 0.f };
                __builtin_nontemporal_store(
                    v, &out4[zbase + (size_t)(d0 + r) * pstr + (size_t)h * (W_ / 4) + w4]);
            }
        }
    }
}

extern "C" void kernel_launch(void* const* d_in, const int* in_sizes, int n_in,
                              void* d_out, int out_size, void* d_ws, size_t ws_size,
                              hipStream_t stream) {
    const float* left  = (const float*)d_in[0];
    const float* right = (const float*)d_in[1];
    float* out = (float*)d_out;

    dim3 block(256);
    dim3 grid(D_ / 4, B_ * 2 * C_);   // (12, 256) = 3072 blocks
    CostVolume_66529043415444_kernel<<<grid, block, 0, stream>>>(left, right, out);
}

// Round 5
// 70.573 us; speedup vs baseline: 1.0067x; 1.0067x over previous
//
#include <hip/hip_runtime.h>

// Problem constants (fixed by setup_inputs): B=4, C=32, H=64, W=128, D=192/4=48.
#define B_  4
#define C_  32
#define H_  64
#define W_  128
#define D_  48
#define HS_ 8          // h-rows per block
#define ROWF_ 200      // LDS floats per row: 128 data + 64 zero tail + 8 pad

typedef float f32x4 __attribute__((ext_vector_type(4)));

// R3 structure (68.6 us), single change: PLAIN stores instead of nontemporal.
// A/B test: does the nt flag's L2 write-policy cost us the last ~10% vs the
// 6.9 TB/s fill-kernel write path?
//
// Output: (B, 2C, D, H, W) float32.
//   ch <  C : out = left[b][ch][h][w]                      (broadcast over d)
//   ch >= C : out = (w+d < W) ? right[b][ch-C][h][w+d] : 0
__global__ __launch_bounds__(256) void CostVolume_66529043415444_kernel(
    const float* __restrict__ left,
    const float* __restrict__ right,
    float* __restrict__ out)
{
    const int tid = threadIdx.x;
    const int w4  = tid & 31;            // float4 index within row: 0..31
    const int hs  = tid >> 5;            // 0..7
    const int h   = (int)blockIdx.x * HS_ + hs;
    const int z   = (int)blockIdx.y;     // b*64 + ch
    const int ch  = z & 63;
    const int b   = z >> 6;

    f32x4* __restrict__ out4 = reinterpret_cast<f32x4*>(out);
    const size_t obase = (((size_t)z * D_) * H_ + h) * (W_ / 4) + w4;
    const size_t dstr  = (size_t)H_ * (W_ / 4);   // 2048 float4 per d-plane

    if (ch < C_) {
        const f32x4* __restrict__ l4 = reinterpret_cast<const f32x4*>(left);
        const f32x4 v = l4[(((size_t)b * C_ + ch) * H_ + h) * (W_ / 4) + w4];
        #pragma unroll
        for (int d = 0; d < D_; ++d)
            out4[obase + (size_t)d * dstr] = v;
    } else {
        __shared__ __align__(16) float rows[HS_][ROWF_];
        const int c = ch - C_;
        const f32x4* __restrict__ r4 =
            reinterpret_cast<const f32x4*>(right + (((size_t)b * C_ + c) * H_ + h) * W_);
        const f32x4 rv = r4[w4];
        *reinterpret_cast<f32x4*>(&rows[hs][w4 * 4]) = rv;
        if (w4 < 16) {
            const f32x4 z4 = {0.f, 0.f, 0.f, 0.f};
            *reinterpret_cast<f32x4*>(&rows[hs][W_ + w4 * 4]) = z4;
        }
        __syncthreads();

        #pragma unroll
        for (int d0 = 0; d0 < D_; d0 += 4) {
            const int k = w4 + (d0 >> 2);
            const f32x4 a  = *reinterpret_cast<const f32x4*>(&rows[hs][k * 4]);
            const f32x4 bb = *reinterpret_cast<const f32x4*>(&rows[hs][k * 4 + 4]);
            const f32x4 v0 = a;
            const f32x4 v1 = {a.y, a.z, a.w, bb.x};
            const f32x4 v2 = {a.z, a.w, bb.x, bb.y};
            const f32x4 v3 = {a.w, bb.x, bb.y, bb.z};
            out4[obase + (size_t)(d0 + 0) * dstr] = v0;
            out4[obase + (size_t)(d0 + 1) * dstr] = v1;
            out4[obase + (size_t)(d0 + 2) * dstr] = v2;
            out4[obase + (size_t)(d0 + 3) * dstr] = v3;
        }
    }
}

extern "C" void kernel_launch(void* const* d_in, const int* in_sizes, int n_in,
                              void* d_out, int out_size, void* d_ws, size_t ws_size,
                              hipStream_t stream) {
    const float* left  = (const float*)d_in[0];
    const float* right = (const float*)d_in[1];
    float* out = (float*)d_out;

    dim3 block(256);
    dim3 grid(H_ / HS_, B_ * 2 * C_);   // (8, 256) = 2048 blocks
    CostVolume_66529043415444_kernel<<<grid, block, 0, stream>>>(left, right, out);
}

// Round 6
// 68.305 us; speedup vs baseline: 1.0401x; 1.0332x over previous
//
#include <hip/hip_runtime.h>

// Problem constants (fixed by setup_inputs): B=4, C=32, H=64, W=128, D=192/4=48.
#define B_  4
#define C_  32
#define H_  64
#define W_  128
#define D_  48
#define HS_ 8          // h-rows per block
#define ROWF_ 200      // LDS floats per row: 128 data + 64 zero tail + 8 pad

typedef float f32x4 __attribute__((ext_vector_type(4)));

// FINAL (= R3, best measured: 68.6 us, 5.87 TB/s effective write BW).
// A/B history: nt vs plain stores: 68.6 vs 70.6; interleaved d-loop vs
// contiguous 4-plane streams: 68.6 vs 71.0. Write-bound roofline:
// 402.7 MB mandatory write at ~85% of the chip's pure-fill BW.
//
// Output: (B, 2C, D, H, W) float32.
//   ch <  C : out = left[b][ch][h][w]                      (broadcast over d)
//   ch >= C : out = (w+d < W) ? right[b][ch-C][h][w+d] : 0
__global__ __launch_bounds__(256) void CostVolume_66529043415444_kernel(
    const float* __restrict__ left,
    const float* __restrict__ right,
    float* __restrict__ out)
{
    const int tid = threadIdx.x;
    const int w4  = tid & 31;            // float4 index within row: 0..31
    const int hs  = tid >> 5;            // 0..7
    const int h   = (int)blockIdx.x * HS_ + hs;
    const int z   = (int)blockIdx.y;     // b*64 + ch
    const int ch  = z & 63;
    const int b   = z >> 6;

    f32x4* __restrict__ out4 = reinterpret_cast<f32x4*>(out);
    const size_t obase = (((size_t)z * D_) * H_ + h) * (W_ / 4) + w4;
    const size_t dstr  = (size_t)H_ * (W_ / 4);   // 2048 float4 per d-plane

    if (ch < C_) {
        // left broadcast: load the row fragment once, store to all 48 d-planes
        const f32x4* __restrict__ l4 = reinterpret_cast<const f32x4*>(left);
        const f32x4 v = l4[(((size_t)b * C_ + ch) * H_ + h) * (W_ / 4) + w4];
        #pragma unroll
        for (int d = 0; d < D_; ++d)
            __builtin_nontemporal_store(v, &out4[obase + (size_t)d * dstr]);
    } else {
        __shared__ __align__(16) float rows[HS_][ROWF_];
        const int c = ch - C_;
        const f32x4* __restrict__ r4 =
            reinterpret_cast<const f32x4*>(right + (((size_t)b * C_ + c) * H_ + h) * W_);
        // stage row into LDS (one float4 per thread), zero the tail 128..191
        const f32x4 rv = r4[w4];
        *reinterpret_cast<f32x4*>(&rows[hs][w4 * 4]) = rv;
        if (w4 < 16) {
            const f32x4 z4 = {0.f, 0.f, 0.f, 0.f};
            *reinterpret_cast<f32x4*>(&rows[hs][W_ + w4 * 4]) = z4;
        }
        __syncthreads();

        #pragma unroll
        for (int d0 = 0; d0 < D_; d0 += 4) {
            // aligned window: floats [4*w4 + d0 .. 4*w4 + d0 + 7]
            const int k = w4 + (d0 >> 2);
            const f32x4 a  = *reinterpret_cast<const f32x4*>(&rows[hs][k * 4]);
            const f32x4 bb = *reinterpret_cast<const f32x4*>(&rows[hs][k * 4 + 4]);
            const f32x4 v0 = a;
            const f32x4 v1 = {a.y, a.z, a.w, bb.x};
            const f32x4 v2 = {a.z, a.w, bb.x, bb.y};
            const f32x4 v3 = {a.w, bb.x, bb.y, bb.z};
            __builtin_nontemporal_store(v0, &out4[obase + (size_t)(d0 + 0) * dstr]);
            __builtin_nontemporal_store(v1, &out4[obase + (size_t)(d0 + 1) * dstr]);
            __builtin_nontemporal_store(v2, &out4[obase + (size_t)(d0 + 2) * dstr]);
            __builtin_nontemporal_store(v3, &out4[obase + (size_t)(d0 + 3) * dstr]);
        }
    }
}

extern "C" void kernel_launch(void* const* d_in, const int* in_sizes, int n_in,
                              void* d_out, int out_size, void* d_ws, size_t ws_size,
                              hipStream_t stream) {
    const float* left  = (const float*)d_in[0];
    const float* right = (const float*)d_in[1];
    float* out = (float*)d_out;

    dim3 block(256);
    dim3 grid(H_ / HS_, B_ * 2 * C_);   // (8, 256) = 2048 blocks
    CostVolume_66529043415444_kernel<<<grid, block, 0, stream>>>(left, right, out);
}